// Round 1
// baseline (4873.681 us; speedup 1.0000x reference)
//
#include <hip/hip_runtime.h>
#include <math.h>

// ComplexFaberConv: N=100000 nodes, E=640000 edges, D=128, K=3 (folded), ALPHA=0.5
//
// Workspace layout (floats):
//   [0, N)              dn_out  (deg_out -> deg_out^-0.25 in place)
//   [N, 2N)             dn_in
//   [2N, 2N+ND)         y_r   = sum_{e:row=r} val*x_real[col]
//   [2N+ND, 2N+2ND)     y_rt  = sum_{e:col=c} val*x_real[row]
//   [2N+2ND, 2N+3ND)    v     = 0.5*(y_i + y_it)  (both scatters, 0.5 folded)
//   then WrT[16384], WiT[16384], b_minus[128], b_plus[128]
// Total ~154.6 MB.

__global__ void deg_kernel(const int* __restrict__ row, const int* __restrict__ col,
                           float* __restrict__ dout, float* __restrict__ din, int E) {
    int e = blockIdx.x * blockDim.x + threadIdx.x;
    if (e < E) {
        atomicAdd(&dout[row[e]], 1.0f);
        atomicAdd(&din[col[e]], 1.0f);
    }
}

__global__ void norm_kernel(float* __restrict__ p, int n) {
    int i = blockIdx.x * blockDim.x + threadIdx.x;
    if (i < n) {
        float d = p[i];
        p[i] = (d > 0.0f) ? powf(d, -0.25f) : 0.0f;
    }
}

// Fold K with s=[1,0.5,0.25] and transpose W to [i][o] layout for coalesced reads.
__global__ void weights_kernel(const float* __restrict__ Wr, const float* __restrict__ Wi,
                               const float* __restrict__ br, const float* __restrict__ bi,
                               float* __restrict__ WrT, float* __restrict__ WiT,
                               float* __restrict__ bm, float* __restrict__ bp) {
    int j = blockIdx.x * blockDim.x + threadIdx.x;  // 0..16383 ; j = o*128 + i
    int o = j >> 7, i = j & 127;
    float wr = Wr[j] + 0.5f * Wr[16384 + j] + 0.25f * Wr[32768 + j];
    float wi = Wi[j] + 0.5f * Wi[16384 + j] + 0.25f * Wi[32768 + j];
    WrT[i * 128 + o] = wr;
    WiT[i * 128 + o] = wi;
    if (j < 128) {
        float er = br[j] + 0.5f * br[128 + j] + 0.25f * br[256 + j];
        float ei = bi[j] + 0.5f * bi[128 + j] + 0.25f * bi[256 + j];
        bm[j] = er - ei;
        bp[j] = er + ei;
    }
}

// One edge per 32-lane group, float4 per lane (32*4 = 128 features).
// 4 scatter targets per edge: y_r[row], y_rt[col], v[row], v[col].
__global__ __launch_bounds__(256) void scatter_kernel(
        const int* __restrict__ row, const int* __restrict__ col,
        const float* __restrict__ dn_out, const float* __restrict__ dn_in,
        const float* __restrict__ xr, const float* __restrict__ xi,
        float* __restrict__ y_r, float* __restrict__ y_t, float* __restrict__ vv, int E) {
    int g = threadIdx.x >> 5;
    int lane = threadIdx.x & 31;
    int e = blockIdx.x * 8 + g;
    if (e >= E) return;
    int r = row[e], c = col[e];
    float val = dn_out[r] * dn_in[c];
    float hv = 0.5f * val;
    const float4* xr4 = (const float4*)xr;
    const float4* xi4 = (const float4*)xi;
    float4 xrc = xr4[(size_t)c * 32 + lane];
    float4 xrr = xr4[(size_t)r * 32 + lane];
    float4 xic = xi4[(size_t)c * 32 + lane];
    float4 xir = xi4[(size_t)r * 32 + lane];
    float* pyr = y_r + (size_t)r * 128 + lane * 4;
    float* pyt = y_t + (size_t)c * 128 + lane * 4;
    float* pvr = vv + (size_t)r * 128 + lane * 4;
    float* pvc = vv + (size_t)c * 128 + lane * 4;
    atomicAdd(pyr + 0, val * xrc.x); atomicAdd(pyr + 1, val * xrc.y);
    atomicAdd(pyr + 2, val * xrc.z); atomicAdd(pyr + 3, val * xrc.w);
    atomicAdd(pyt + 0, val * xrr.x); atomicAdd(pyt + 1, val * xrr.y);
    atomicAdd(pyt + 2, val * xrr.z); atomicAdd(pyt + 3, val * xrr.w);
    atomicAdd(pvr + 0, hv * xic.x);  atomicAdd(pvr + 1, hv * xic.y);
    atomicAdd(pvr + 2, hv * xic.z);  atomicAdd(pvr + 3, hv * xic.w);
    atomicAdd(pvc + 0, hv * xir.x);  atomicAdd(pvc + 1, hv * xir.y);
    atomicAdd(pvc + 2, hv * xir.z);  atomicAdd(pvc + 3, hv * xir.w);
}

// 64 nodes per block, 256 threads: threads 0..127 compute out_real[o], 128..255 out_imag[o].
// real: sum_i u[i]*WrT[i][o] - v[i]*WiT[i][o] + bm[o]
// imag: sum_i yr[i]*WiT[i][o] + v[i]*WrT[i][o] + bp[o]   (yr, faithful to source)
// 8-node register blocking: each W value loaded once feeds 8 FMAs.
__global__ __launch_bounds__(256) void out_kernel(
        const float* __restrict__ y_r, const float* __restrict__ y_t, const float* __restrict__ vv,
        const float* __restrict__ WrT, const float* __restrict__ WiT,
        const float* __restrict__ bm, const float* __restrict__ bp,
        float* __restrict__ out, int N) {
    __shared__ float su[8][128];
    __shared__ float sv[8][128];
    __shared__ float sy[8][128];
    int tid = threadIdx.x;
    int o = tid & 127;
    int path = tid >> 7;  // 0: real, 1: imag
    size_t ND = (size_t)N * 128;
    const float* WA = path ? WiT : WrT;
    const float* WB = path ? WrT : WiT;
    float sgn = path ? 1.0f : -1.0f;
    float bias = path ? bp[o] : bm[o];
    int nbase = blockIdx.x * 64;

    for (int g = 0; g < 8; ++g) {
        __syncthreads();
        for (int idx = tid; idx < 1024; idx += 256) {
            int nn = idx >> 7, ii = idx & 127;
            int n = nbase + g * 8 + nn;
            float a = 0.0f, b = 0.0f, c = 0.0f;
            if (n < N) {
                a = y_r[(size_t)n * 128 + ii];
                b = y_t[(size_t)n * 128 + ii];
                c = vv[(size_t)n * 128 + ii];
            }
            su[nn][ii] = 0.5f * (a + b);
            sy[nn][ii] = a;
            sv[nn][ii] = c;
        }
        __syncthreads();
        const float (*SA)[128] = path ? sy : su;
        float acc[8] = {0, 0, 0, 0, 0, 0, 0, 0};
        for (int i = 0; i < 128; i += 4) {
            float wa0 = WA[(i + 0) * 128 + o];
            float wa1 = WA[(i + 1) * 128 + o];
            float wa2 = WA[(i + 2) * 128 + o];
            float wa3 = WA[(i + 3) * 128 + o];
            float wb0 = sgn * WB[(i + 0) * 128 + o];
            float wb1 = sgn * WB[(i + 1) * 128 + o];
            float wb2 = sgn * WB[(i + 2) * 128 + o];
            float wb3 = sgn * WB[(i + 3) * 128 + o];
#pragma unroll
            for (int nn = 0; nn < 8; ++nn) {
                float4 a4 = *(const float4*)&SA[nn][i];
                float4 b4 = *(const float4*)&sv[nn][i];
                acc[nn] = fmaf(a4.x, wa0, acc[nn]);
                acc[nn] = fmaf(a4.y, wa1, acc[nn]);
                acc[nn] = fmaf(a4.z, wa2, acc[nn]);
                acc[nn] = fmaf(a4.w, wa3, acc[nn]);
                acc[nn] = fmaf(b4.x, wb0, acc[nn]);
                acc[nn] = fmaf(b4.y, wb1, acc[nn]);
                acc[nn] = fmaf(b4.z, wb2, acc[nn]);
                acc[nn] = fmaf(b4.w, wb3, acc[nn]);
            }
        }
        for (int nn = 0; nn < 8; ++nn) {
            int n = nbase + g * 8 + nn;
            if (n < N) out[(size_t)path * ND + (size_t)n * 128 + o] = acc[nn] + bias;
        }
    }
}

extern "C" void kernel_launch(void* const* d_in, const int* in_sizes, int n_in,
                              void* d_out, int out_size, void* d_ws, size_t ws_size,
                              hipStream_t stream) {
    const float* x_real = (const float*)d_in[0];
    const float* x_imag = (const float*)d_in[1];
    const float* W_real = (const float*)d_in[2];
    const float* W_imag = (const float*)d_in[3];
    const float* b_real = (const float*)d_in[4];
    const float* b_imag = (const float*)d_in[5];
    const int* edge = (const int*)d_in[6];

    int N = in_sizes[0] / 128;
    int E = in_sizes[6] / 2;
    const int* row = edge;
    const int* col = edge + E;
    float* out = (float*)d_out;

    float* ws = (float*)d_ws;
    size_t ND = (size_t)N * 128;
    float* dn_out = ws;
    float* dn_in = ws + N;
    float* y_r = ws + 2 * (size_t)N;
    float* y_t = y_r + ND;
    float* vv = y_t + ND;
    float* WrT = vv + ND;
    float* WiT = WrT + 16384;
    float* bm = WiT + 16384;
    float* bp = bm + 128;

    // zero degree counters + the three accumulators (contiguous from offset 0)
    size_t zero_bytes = (2 * (size_t)N + 3 * ND) * sizeof(float);
    hipMemsetAsync(d_ws, 0, zero_bytes, stream);

    deg_kernel<<<(E + 255) / 256, 256, 0, stream>>>(row, col, dn_out, dn_in, E);
    norm_kernel<<<(2 * N + 255) / 256, 256, 0, stream>>>(dn_out, 2 * N);
    weights_kernel<<<64, 256, 0, stream>>>(W_real, W_imag, b_real, b_imag, WrT, WiT, bm, bp);
    scatter_kernel<<<(E + 7) / 8, 256, 0, stream>>>(row, col, dn_out, dn_in,
                                                    x_real, x_imag, y_r, y_t, vv, E);
    out_kernel<<<(N + 63) / 64, 256, 0, stream>>>(y_r, y_t, vv, WrT, WiT, bm, bp, out, N);
}

// Round 2
// 863.117 us; speedup vs baseline: 5.6466x; 5.6466x over previous
//
#include <hip/hip_runtime.h>
#include <math.h>

// ComplexFaberConv — CSR-gather version (no float atomics).
//
// Workspace (bytes, N=100000, E=640000):
//   cnt  int[2N]    @ 0          (row counts [0,N), col counts [N,2N))
//   off  int[2N]    @ +800000    (exclusive scan; mutated to "end" by fill)
//   bsum int[1024]  @ +1600000
//   dn   float[2N]  @ +1604096   (deg^-0.25; dn_out=[0,N), dn_in=[N,2N))
//   idx  int[2E]    @ +2404096   (by-row neighbor lists then by-col)
//   y_r,y_t,vv float[ND] each @ +7524096
//   WrT,WiT[16384], bm,bp[128]
// Total ~161.3 MB.

__global__ void count_kernel(const int* __restrict__ row, const int* __restrict__ col,
                             int* __restrict__ cnt, int N, int E) {
    int e = blockIdx.x * blockDim.x + threadIdx.x;
    if (e < E) {
        atomicAdd(&cnt[row[e]], 1);
        atomicAdd(&cnt[N + col[e]], 1);
    }
}

__global__ void norm_kernel(const int* __restrict__ cnt, float* __restrict__ dn, int n2) {
    int i = blockIdx.x * blockDim.x + threadIdx.x;
    if (i < n2) {
        int d = cnt[i];
        dn[i] = (d > 0) ? rsqrtf(sqrtf((float)d)) : 0.0f;  // d^-0.25
    }
}

__global__ void scan1_kernel(const int* __restrict__ cnt, int* __restrict__ bsum, int n2) {
    __shared__ int tmp[256];
    int t = threadIdx.x, i = blockIdx.x * 256 + t;
    tmp[t] = (i < n2) ? cnt[i] : 0;
    __syncthreads();
    for (int d = 128; d > 0; d >>= 1) {
        if (t < d) tmp[t] += tmp[t + d];
        __syncthreads();
    }
    if (t == 0) bsum[blockIdx.x] = tmp[0];
}

__global__ void scan2_kernel(int* __restrict__ bsum, int nb) {
    __shared__ int tmp[1024];
    int t = threadIdx.x;
    int v = (t < nb) ? bsum[t] : 0;
    tmp[t] = v;
    for (int d = 1; d < 1024; d <<= 1) {
        __syncthreads();
        int u = (t >= d) ? tmp[t - d] : 0;
        __syncthreads();
        tmp[t] += u;
    }
    __syncthreads();
    if (t < nb) bsum[t] = tmp[t] - v;  // exclusive
}

__global__ void scan3_kernel(const int* __restrict__ cnt, const int* __restrict__ bsum,
                             int* __restrict__ off, int n2) {
    __shared__ int tmp[256];
    int t = threadIdx.x, i = blockIdx.x * 256 + t;
    int v = (i < n2) ? cnt[i] : 0;
    tmp[t] = v;
    for (int d = 1; d < 256; d <<= 1) {
        __syncthreads();
        int u = (t >= d) ? tmp[t - d] : 0;
        __syncthreads();
        tmp[t] += u;
    }
    __syncthreads();
    if (i < n2) off[i] = tmp[t] - v + bsum[blockIdx.x];
}

__global__ void fill_kernel(const int* __restrict__ row, const int* __restrict__ col,
                            int* __restrict__ off, int* __restrict__ idx, int N, int E) {
    int e = blockIdx.x * blockDim.x + threadIdx.x;
    if (e < E) {
        int r = row[e], c = col[e];
        int p = atomicAdd(&off[r], 1);      idx[p] = c;
        int q = atomicAdd(&off[N + c], 1);  idx[q] = r;
    }
}

__global__ void weights_kernel(const float* __restrict__ Wr, const float* __restrict__ Wi,
                               const float* __restrict__ br, const float* __restrict__ bi,
                               float* __restrict__ WrT, float* __restrict__ WiT,
                               float* __restrict__ bm, float* __restrict__ bp) {
    int j = blockIdx.x * blockDim.x + threadIdx.x;  // j = o*128 + i
    int o = j >> 7, i = j & 127;
    float wr = Wr[j] + 0.5f * Wr[16384 + j] + 0.25f * Wr[32768 + j];
    float wi = Wi[j] + 0.5f * Wi[16384 + j] + 0.25f * Wi[32768 + j];
    WrT[i * 128 + o] = wr;
    WiT[i * 128 + o] = wi;
    if (j < 128) {
        float er = br[j] + 0.5f * br[128 + j] + 0.25f * br[256 + j];
        float ei = bi[j] + 0.5f * bi[128 + j] + 0.25f * bi[256 + j];
        bm[j] = er - ei;
        bp[j] = er + ei;
    }
}

// One 64-lane wave per node; lane holds features (2l, 2l+1) as float2.
// After fill, off[k] is the END of bucket k; start = off[k] - cnt[k].
__global__ __launch_bounds__(256) void gather_kernel(
        const int* __restrict__ off, const int* __restrict__ cnt,
        const int* __restrict__ idx, const float* __restrict__ dn,
        const float* __restrict__ xr, const float* __restrict__ xi,
        float* __restrict__ y_r, float* __restrict__ y_t, float* __restrict__ vv, int N) {
    int wave = (blockIdx.x * blockDim.x + threadIdx.x) >> 6;
    int lane = threadIdx.x & 63;
    if (wave >= N) return;
    int n = wave;
    const float2* xr2 = (const float2*)xr;
    const float2* xi2 = (const float2*)xi;

    // row pass: neighbors c of out-edges (n -> c); weight dn_in[c]
    float2 aR = {0.f, 0.f}, aI = {0.f, 0.f};
    {
        int end = off[n], start = end - cnt[n];
        for (int j = start; j < end; ++j) {
            int c = idx[j];
            float w = dn[N + c];
            float2 r = xr2[(size_t)c * 64 + lane];
            float2 m = xi2[(size_t)c * 64 + lane];
            aR.x = fmaf(w, r.x, aR.x); aR.y = fmaf(w, r.y, aR.y);
            aI.x = fmaf(w, m.x, aI.x); aI.y = fmaf(w, m.y, aI.y);
        }
    }
    // col pass: neighbors r of in-edges (r -> n); weight dn_out[r]
    float2 bR = {0.f, 0.f}, bI = {0.f, 0.f};
    {
        int end = off[N + n], start = end - cnt[N + n];
        for (int j = start; j < end; ++j) {
            int r_ = idx[j];
            float w = dn[r_];
            float2 r = xr2[(size_t)r_ * 64 + lane];
            float2 m = xi2[(size_t)r_ * 64 + lane];
            bR.x = fmaf(w, r.x, bR.x); bR.y = fmaf(w, r.y, bR.y);
            bI.x = fmaf(w, m.x, bI.x); bI.y = fmaf(w, m.y, bI.y);
        }
    }
    float wo = dn[n], wi_ = dn[N + n];
    size_t p = (size_t)n * 64 + lane;
    ((float2*)y_r)[p] = make_float2(wo * aR.x, wo * aR.y);
    ((float2*)y_t)[p] = make_float2(wi_ * bR.x, wi_ * bR.y);
    ((float2*)vv)[p] = make_float2(0.5f * (wo * aI.x + wi_ * bI.x),
                                   0.5f * (wo * aI.y + wi_ * bI.y));
}

// 64 nodes per block, 256 threads: 0..127 -> out_real[o], 128..255 -> out_imag[o].
__global__ __launch_bounds__(256) void out_kernel(
        const float* __restrict__ y_r, const float* __restrict__ y_t, const float* __restrict__ vv,
        const float* __restrict__ WrT, const float* __restrict__ WiT,
        const float* __restrict__ bm, const float* __restrict__ bp,
        float* __restrict__ out, int N) {
    __shared__ float su[8][128];
    __shared__ float sv[8][128];
    __shared__ float sy[8][128];
    int tid = threadIdx.x;
    int o = tid & 127;
    int path = tid >> 7;
    size_t ND = (size_t)N * 128;
    const float* WA = path ? WiT : WrT;
    const float* WB = path ? WrT : WiT;
    float sgn = path ? 1.0f : -1.0f;
    float bias = path ? bp[o] : bm[o];
    int nbase = blockIdx.x * 64;

    for (int g = 0; g < 8; ++g) {
        __syncthreads();
        for (int idx2 = tid; idx2 < 1024; idx2 += 256) {
            int nn = idx2 >> 7, ii = idx2 & 127;
            int n = nbase + g * 8 + nn;
            float a = 0.0f, b = 0.0f, c = 0.0f;
            if (n < N) {
                a = y_r[(size_t)n * 128 + ii];
                b = y_t[(size_t)n * 128 + ii];
                c = vv[(size_t)n * 128 + ii];
            }
            su[nn][ii] = 0.5f * (a + b);
            sy[nn][ii] = a;
            sv[nn][ii] = c;
        }
        __syncthreads();
        const float (*SA)[128] = path ? sy : su;
        float acc[8] = {0, 0, 0, 0, 0, 0, 0, 0};
        for (int i = 0; i < 128; i += 4) {
            float wa0 = WA[(i + 0) * 128 + o];
            float wa1 = WA[(i + 1) * 128 + o];
            float wa2 = WA[(i + 2) * 128 + o];
            float wa3 = WA[(i + 3) * 128 + o];
            float wb0 = sgn * WB[(i + 0) * 128 + o];
            float wb1 = sgn * WB[(i + 1) * 128 + o];
            float wb2 = sgn * WB[(i + 2) * 128 + o];
            float wb3 = sgn * WB[(i + 3) * 128 + o];
#pragma unroll
            for (int nn = 0; nn < 8; ++nn) {
                float4 a4 = *(const float4*)&SA[nn][i];
                float4 b4 = *(const float4*)&sv[nn][i];
                acc[nn] = fmaf(a4.x, wa0, acc[nn]);
                acc[nn] = fmaf(a4.y, wa1, acc[nn]);
                acc[nn] = fmaf(a4.z, wa2, acc[nn]);
                acc[nn] = fmaf(a4.w, wa3, acc[nn]);
                acc[nn] = fmaf(b4.x, wb0, acc[nn]);
                acc[nn] = fmaf(b4.y, wb1, acc[nn]);
                acc[nn] = fmaf(b4.z, wb2, acc[nn]);
                acc[nn] = fmaf(b4.w, wb3, acc[nn]);
            }
        }
        for (int nn = 0; nn < 8; ++nn) {
            int n = nbase + g * 8 + nn;
            if (n < N) out[(size_t)path * ND + (size_t)n * 128 + o] = acc[nn] + bias;
        }
    }
}

extern "C" void kernel_launch(void* const* d_in, const int* in_sizes, int n_in,
                              void* d_out, int out_size, void* d_ws, size_t ws_size,
                              hipStream_t stream) {
    const float* x_real = (const float*)d_in[0];
    const float* x_imag = (const float*)d_in[1];
    const float* W_real = (const float*)d_in[2];
    const float* W_imag = (const float*)d_in[3];
    const float* b_real = (const float*)d_in[4];
    const float* b_imag = (const float*)d_in[5];
    const int* edge = (const int*)d_in[6];

    int N = in_sizes[0] / 128;
    int E = in_sizes[6] / 2;
    const int* row = edge;
    const int* col = edge + E;
    float* out = (float*)d_out;

    char* ws = (char*)d_ws;
    size_t ND = (size_t)N * 128;
    int* cnt = (int*)ws;                               // 2N ints
    int* off = (int*)(ws + (size_t)2 * N * 4);         // 2N ints
    int* bsum = (int*)(ws + (size_t)4 * N * 4);        // 1024 ints
    float* dn = (float*)(ws + (size_t)4 * N * 4 + 4096);       // 2N floats
    int* idx = (int*)(ws + (size_t)6 * N * 4 + 4096);          // 2E ints
    float* y_r = (float*)(ws + (size_t)6 * N * 4 + 4096 + (size_t)2 * E * 4);
    float* y_t = y_r + ND;
    float* vv = y_t + ND;
    float* WrT = vv + ND;
    float* WiT = WrT + 16384;
    float* bm = WiT + 16384;
    float* bp = bm + 128;

    int n2 = 2 * N;
    int nb = (n2 + 255) / 256;  // 782 <= 1024

    hipMemsetAsync(cnt, 0, (size_t)n2 * 4, stream);
    count_kernel<<<(E + 255) / 256, 256, 0, stream>>>(row, col, cnt, N, E);
    norm_kernel<<<(n2 + 255) / 256, 256, 0, stream>>>(cnt, dn, n2);
    scan1_kernel<<<nb, 256, 0, stream>>>(cnt, bsum, n2);
    scan2_kernel<<<1, 1024, 0, stream>>>(bsum, nb);
    scan3_kernel<<<nb, 256, 0, stream>>>(cnt, bsum, off, n2);
    fill_kernel<<<(E + 255) / 256, 256, 0, stream>>>(row, col, off, idx, N, E);
    weights_kernel<<<64, 256, 0, stream>>>(W_real, W_imag, b_real, b_imag, WrT, WiT, bm, bp);
    gather_kernel<<<(N * 64 + 255) / 256, 256, 0, stream>>>(off, cnt, idx, dn,
                                                            x_real, x_imag, y_r, y_t, vv, N);
    out_kernel<<<(N + 63) / 64, 256, 0, stream>>>(y_r, y_t, vv, WrT, WiT, bm, bp, out, N);
}

// Round 3
// 590.711 us; speedup vs baseline: 8.2505x; 1.4611x over previous
//
#include <hip/hip_runtime.h>
#include <math.h>

// ComplexFaberConv — CSR gather (f32) -> bf16 A matrix -> MFMA GEMM.
//
// A[n] = [u(128) | v(128) | yr(128)] bf16, row stride 384.
//   u  = 0.5*(y_r + y_rt), v = 0.5*(y_i + y_it), yr = y_r
// real = u@Wr_eff^T - v@Wi_eff^T + (br-bi)   (A slice [0:256))
// imag = v@Wr_eff^T + yr@Wi_eff^T + (br+bi)  (A slice [128:384))
//
// Workspace (bytes, N=100000, E=640000, Npad=100096):
//   cnt  int[2N]           @ 0
//   off  int[2N]           @ 800000
//   bsum int[1024]         @ 1600000
//   dn   float[2N]         @ 1604096
//   idx  int[2E]           @ 2404096
//   Wt   bf16[2][128][256] @ 7524096   (combined per-path weights)
//   bias f32[2][128]       @ 7655168
//   A    bf16[Npad][384]   @ 7656192   (~76.9 MB)
// Total ~84.5 MB.

typedef __bf16 bf16x8 __attribute__((ext_vector_type(8)));
typedef float f32x4 __attribute__((ext_vector_type(4)));

__device__ __forceinline__ unsigned short f2b(float f) {
    // RNE float->bf16 (NaN not expected in this data)
    unsigned u = __float_as_uint(f);
    u += 0x7FFFu + ((u >> 16) & 1u);
    return (unsigned short)(u >> 16);
}
__device__ __forceinline__ unsigned pk(float lo, float hi) {
    return (unsigned)f2b(lo) | ((unsigned)f2b(hi) << 16);
}

__global__ void count_kernel(const int* __restrict__ row, const int* __restrict__ col,
                             int* __restrict__ cnt, int N, int E) {
    int e = blockIdx.x * blockDim.x + threadIdx.x;
    if (e < E) {
        atomicAdd(&cnt[row[e]], 1);
        atomicAdd(&cnt[N + col[e]], 1);
    }
}

__global__ void norm_kernel(const int* __restrict__ cnt, float* __restrict__ dn, int n2) {
    int i = blockIdx.x * blockDim.x + threadIdx.x;
    if (i < n2) {
        int d = cnt[i];
        dn[i] = (d > 0) ? rsqrtf(sqrtf((float)d)) : 0.0f;  // d^-0.25
    }
}

__global__ void scan1_kernel(const int* __restrict__ cnt, int* __restrict__ bsum, int n2) {
    __shared__ int tmp[256];
    int t = threadIdx.x, i = blockIdx.x * 256 + t;
    tmp[t] = (i < n2) ? cnt[i] : 0;
    __syncthreads();
    for (int d = 128; d > 0; d >>= 1) {
        if (t < d) tmp[t] += tmp[t + d];
        __syncthreads();
    }
    if (t == 0) bsum[blockIdx.x] = tmp[0];
}

__global__ void scan2_kernel(int* __restrict__ bsum, int nb) {
    __shared__ int tmp[1024];
    int t = threadIdx.x;
    int v = (t < nb) ? bsum[t] : 0;
    tmp[t] = v;
    for (int d = 1; d < 1024; d <<= 1) {
        __syncthreads();
        int u = (t >= d) ? tmp[t - d] : 0;
        __syncthreads();
        tmp[t] += u;
    }
    __syncthreads();
    if (t < nb) bsum[t] = tmp[t] - v;  // exclusive
}

__global__ void scan3_kernel(const int* __restrict__ cnt, const int* __restrict__ bsum,
                             int* __restrict__ off, int n2) {
    __shared__ int tmp[256];
    int t = threadIdx.x, i = blockIdx.x * 256 + t;
    int v = (i < n2) ? cnt[i] : 0;
    tmp[t] = v;
    for (int d = 1; d < 256; d <<= 1) {
        __syncthreads();
        int u = (t >= d) ? tmp[t - d] : 0;
        __syncthreads();
        tmp[t] += u;
    }
    __syncthreads();
    if (i < n2) off[i] = tmp[t] - v + bsum[blockIdx.x];
}

__global__ void fill_kernel(const int* __restrict__ row, const int* __restrict__ col,
                            int* __restrict__ off, int* __restrict__ idx, int N, int E) {
    int e = blockIdx.x * blockDim.x + threadIdx.x;
    if (e < E) {
        int r = row[e], c = col[e];
        int p = atomicAdd(&off[r], 1);      idx[p] = c;
        int q = atomicAdd(&off[N + c], 1);  idx[q] = r;
    }
}

// Build combined per-path weights Wt[path][o][k] (bf16) and bias[path][o].
// path0 (real): k<128 -> Wr_eff[o][k] (u), k>=128 -> -Wi_eff[o][k-128] (v)
// path1 (imag): k<128 -> Wr_eff[o][k] (v), k>=128 ->  Wi_eff[o][k-128] (yr)
__global__ void weights_kernel(const float* __restrict__ Wr, const float* __restrict__ Wi,
                               const float* __restrict__ br, const float* __restrict__ bi,
                               unsigned short* __restrict__ Wt, float* __restrict__ bias) {
    int j = blockIdx.x * 256 + threadIdx.x;  // 0..65535
    int k = j & 255, o = (j >> 8) & 127, path = j >> 15;
    int i = k & 127;
    float wr = Wr[o * 128 + i] + 0.5f * Wr[16384 + o * 128 + i] + 0.25f * Wr[32768 + o * 128 + i];
    float wi = Wi[o * 128 + i] + 0.5f * Wi[16384 + o * 128 + i] + 0.25f * Wi[32768 + o * 128 + i];
    float v;
    if (path == 0) v = (k < 128) ? wr : -wi;
    else           v = (k < 128) ? wr : wi;
    Wt[j] = f2b(v);
    if (j < 256) {
        int oo = j & 127, p = j >> 7;
        float er = br[oo] + 0.5f * br[128 + oo] + 0.25f * br[256 + oo];
        float ei = bi[oo] + 0.5f * bi[128 + oo] + 0.25f * bi[256 + oo];
        bias[j] = p ? (er + ei) : (er - ei);
    }
}

// One 64-lane wave per node; lane holds features (2l, 2l+1). f32 math, bf16 out.
__global__ __launch_bounds__(256) void gather_kernel(
        const int* __restrict__ off, const int* __restrict__ cnt,
        const int* __restrict__ idx, const float* __restrict__ dn,
        const float* __restrict__ xr, const float* __restrict__ xi,
        unsigned int* __restrict__ A, int N) {  // A as uint pairs, row stride 192
    int wave = (blockIdx.x * blockDim.x + threadIdx.x) >> 6;
    int lane = threadIdx.x & 63;
    if (wave >= N) return;
    int n = wave;
    const float2* xr2 = (const float2*)xr;
    const float2* xi2 = (const float2*)xi;

    float2 aR = {0.f, 0.f}, aI = {0.f, 0.f};
    {
        int end = off[n], start = end - cnt[n];
        for (int j = start; j < end; ++j) {
            int c = idx[j];
            float w = dn[N + c];
            float2 r = xr2[(size_t)c * 64 + lane];
            float2 m = xi2[(size_t)c * 64 + lane];
            aR.x = fmaf(w, r.x, aR.x); aR.y = fmaf(w, r.y, aR.y);
            aI.x = fmaf(w, m.x, aI.x); aI.y = fmaf(w, m.y, aI.y);
        }
    }
    float2 bR = {0.f, 0.f}, bI = {0.f, 0.f};
    {
        int end = off[N + n], start = end - cnt[N + n];
        for (int j = start; j < end; ++j) {
            int r_ = idx[j];
            float w = dn[r_];
            float2 r = xr2[(size_t)r_ * 64 + lane];
            float2 m = xi2[(size_t)r_ * 64 + lane];
            bR.x = fmaf(w, r.x, bR.x); bR.y = fmaf(w, r.y, bR.y);
            bI.x = fmaf(w, m.x, bI.x); bI.y = fmaf(w, m.y, bI.y);
        }
    }
    float wo = dn[n], wi_ = dn[N + n];
    float yrx = wo * aR.x, yry = wo * aR.y;
    float ux = 0.5f * (yrx + wi_ * bR.x), uy = 0.5f * (yry + wi_ * bR.y);
    float vx = 0.5f * (wo * aI.x + wi_ * bI.x), vy = 0.5f * (wo * aI.y + wi_ * bI.y);
    unsigned int* rowp = A + (size_t)n * 192;
    rowp[lane]       = pk(ux, uy);
    rowp[64 + lane]  = pk(vx, vy);
    rowp[128 + lane] = pk(yrx, yry);
}

// BM=128, BN=128 (full path width), K=256. 4 waves (2x2), 64x64 per wave.
// A staged to linear LDS via global_load_lds with source-side XOR swizzle
// (chunk ^= row&7); W fragments read directly from global (L2-resident).
__global__ __launch_bounds__(256) void mfma_out_kernel(
        const unsigned short* __restrict__ A,   // [Npad][384] bf16 bits
        const unsigned short* __restrict__ Wt,  // [2][128][256] bf16 bits
        const float* __restrict__ bias,         // [2][128]
        float* __restrict__ out, int N) {
    __shared__ unsigned short Alds[128 * 256];  // 64 KB
    int path = blockIdx.y;
    int mbase = blockIdx.x * 128;
    int tid = threadIdx.x;
    int lane = tid & 63, wid = tid >> 6;

    // Stage A slice: 128 rows x 256 bf16 (512B/row), 16 chunk-iters.
    const unsigned short* Ag = A + (size_t)mbase * 384 + path * 128;
#pragma unroll
    for (int i = 0; i < 16; ++i) {
        int linear = i * 256 + tid;           // 16B-chunk index
        int row = linear >> 5, chunk = linear & 31;
        int gchunk = chunk ^ (row & 7);       // inverse-swizzled source
        const unsigned short* gp = Ag + (size_t)row * 384 + gchunk * 8;
        char* lp = (char*)Alds + (size_t)(i * 256 + wid * 64) * 16;  // wave-uniform
        __builtin_amdgcn_global_load_lds(
            (const __attribute__((address_space(1))) void*)gp,
            (__attribute__((address_space(3))) void*)lp, 16, 0, 0);
    }
    __syncthreads();

    int wm = wid >> 1, wn = wid & 1;
    int r0 = wm * 64, c0 = wn * 64;
    f32x4 acc[4][4] = {};
    const unsigned short* Wp = Wt + ((size_t)path * 128 + c0 + (lane & 15)) * 256 + (lane >> 4) * 8;

    for (int kk = 0; kk < 8; ++kk) {
        bf16x8 b[4];
#pragma unroll
        for (int ni = 0; ni < 4; ++ni)
            b[ni] = *(const bf16x8*)(Wp + (size_t)ni * 16 * 256 + kk * 32);
        bf16x8 a[4];
#pragma unroll
        for (int mi = 0; mi < 4; ++mi) {
            int row = r0 + mi * 16 + (lane & 15);
            int chunk = (kk * 4 + (lane >> 4)) ^ (row & 7);  // swizzled read
            a[mi] = *(const bf16x8*)(Alds + row * 256 + chunk * 8);
        }
#pragma unroll
        for (int mi = 0; mi < 4; ++mi)
#pragma unroll
            for (int ni = 0; ni < 4; ++ni)
                acc[mi][ni] = __builtin_amdgcn_mfma_f32_16x16x32_bf16(a[mi], b[ni], acc[mi][ni], 0, 0, 0);
    }

    size_t ND = (size_t)N * 128;
#pragma unroll
    for (int mi = 0; mi < 4; ++mi) {
#pragma unroll
        for (int ni = 0; ni < 4; ++ni) {
            int col = c0 + ni * 16 + (lane & 15);
            float bb = bias[path * 128 + col];
#pragma unroll
            for (int r = 0; r < 4; ++r) {
                int n = mbase + r0 + mi * 16 + (lane >> 4) * 4 + r;
                if (n < N) out[(size_t)path * ND + (size_t)n * 128 + col] = acc[mi][ni][r] + bb;
            }
        }
    }
}

extern "C" void kernel_launch(void* const* d_in, const int* in_sizes, int n_in,
                              void* d_out, int out_size, void* d_ws, size_t ws_size,
                              hipStream_t stream) {
    const float* x_real = (const float*)d_in[0];
    const float* x_imag = (const float*)d_in[1];
    const float* W_real = (const float*)d_in[2];
    const float* W_imag = (const float*)d_in[3];
    const float* b_real = (const float*)d_in[4];
    const float* b_imag = (const float*)d_in[5];
    const int* edge = (const int*)d_in[6];

    int N = in_sizes[0] / 128;
    int E = in_sizes[6] / 2;
    const int* row = edge;
    const int* col = edge + E;
    float* out = (float*)d_out;

    char* ws = (char*)d_ws;
    int n2 = 2 * N;
    int Npad = ((N + 127) / 128) * 128;
    int* cnt = (int*)ws;
    int* off = (int*)(ws + (size_t)n2 * 4);
    int* bsum = (int*)(ws + (size_t)2 * n2 * 4);
    float* dn = (float*)(ws + (size_t)2 * n2 * 4 + 4096);
    int* idx = (int*)(ws + (size_t)3 * n2 * 4 + 4096);
    unsigned short* Wt = (unsigned short*)(ws + (size_t)3 * n2 * 4 + 4096 + (size_t)2 * E * 4);
    float* bias = (float*)((char*)Wt + 2 * 128 * 256 * 2);
    unsigned short* A = (unsigned short*)((char*)bias + 256 * 4);

    int nb = (n2 + 255) / 256;  // <= 1024

    hipMemsetAsync(cnt, 0, (size_t)n2 * 4, stream);
    count_kernel<<<(E + 255) / 256, 256, 0, stream>>>(row, col, cnt, N, E);
    norm_kernel<<<(n2 + 255) / 256, 256, 0, stream>>>(cnt, dn, n2);
    scan1_kernel<<<nb, 256, 0, stream>>>(cnt, bsum, n2);
    scan2_kernel<<<1, 1024, 0, stream>>>(bsum, nb);
    scan3_kernel<<<nb, 256, 0, stream>>>(cnt, bsum, off, n2);
    fill_kernel<<<(E + 255) / 256, 256, 0, stream>>>(row, col, off, idx, N, E);
    weights_kernel<<<256, 256, 0, stream>>>(W_real, W_imag, b_real, b_imag, Wt, bias);
    gather_kernel<<<(N * 64 + 255) / 256, 256, 0, stream>>>(off, cnt, idx, dn,
                                                            x_real, x_imag,
                                                            (unsigned int*)A, N);
    dim3 gg(Npad / 128, 2);
    mfma_out_kernel<<<gg, 256, 0, stream>>>(A, Wt, bias, out, N);
}

// Round 4
// 539.123 us; speedup vs baseline: 9.0400x; 1.0957x over previous
//
#include <hip/hip_runtime.h>
#include <math.h>

// ComplexFaberConv — CSR gather over bf16-packed X -> bf16 A -> MFMA GEMM.
//
// Xp[n] = [xr(128) | xi(128)] bf16 (512B row), built once from f32 x.
// A[n]  = [u(128) | v(128) | yr(128)] bf16, row stride 384.
//   u = 0.5*(y_r + y_rt), v = 0.5*(y_i + y_it), yr = y_r
// real = u@Wr_eff^T - v@Wi_eff^T + (br-bi)   (A k-slice [0:256))
// imag = v@Wr_eff^T + yr@Wi_eff^T + (br+bi)  (A k-slice [128:384))
//
// Workspace (N=100000, E=640000, Npad=100096):
//   cnt  int[2N]            @ 0
//   off  int[2N]            @ 800000
//   bsum int[1024]          @ 1600000
//   dn   float[2N]          @ 1604096
//   idx2 int2[2E]           @ 2404096   (neighbor, dn-weight bits)
//   Xp   uint[N*128]        @ 7524096   (bf16 pairs, 51.2MB)
//   Wt   bf16[2][128][256]  @ 58724096
//   bias f32[2][128]        @ 58855168
//   A    bf16[Npad][384]    @ 58856192  (~76.9MB)
// Total ~135.7 MB.

typedef __bf16 bf16x8 __attribute__((ext_vector_type(8)));
typedef float f32x4 __attribute__((ext_vector_type(4)));

__device__ __forceinline__ unsigned short f2b(float f) {
    unsigned u = __float_as_uint(f);
    u += 0x7FFFu + ((u >> 16) & 1u);
    return (unsigned short)(u >> 16);
}
__device__ __forceinline__ unsigned pk(float lo, float hi) {
    return (unsigned)f2b(lo) | ((unsigned)f2b(hi) << 16);
}
__device__ __forceinline__ float2 b2f2(unsigned w) {
    return make_float2(__uint_as_float(w << 16), __uint_as_float(w & 0xFFFF0000u));
}

__global__ void count_kernel(const int* __restrict__ row, const int* __restrict__ col,
                             int* __restrict__ cnt, int N, int E) {
    int e = blockIdx.x * blockDim.x + threadIdx.x;
    if (e < E) {
        atomicAdd(&cnt[row[e]], 1);
        atomicAdd(&cnt[N + col[e]], 1);
    }
}

// Per-256 block sums + dn = deg^-0.25 (norm folded in).
__global__ void scan1_kernel(const int* __restrict__ cnt, int* __restrict__ bsum,
                             float* __restrict__ dn, int n2) {
    __shared__ int tmp[256];
    int t = threadIdx.x, i = blockIdx.x * 256 + t;
    int d = (i < n2) ? cnt[i] : 0;
    if (i < n2) dn[i] = (d > 0) ? rsqrtf(sqrtf((float)d)) : 0.0f;
    tmp[t] = d;
    __syncthreads();
    for (int s = 128; s > 0; s >>= 1) {
        if (t < s) tmp[t] += tmp[t + s];
        __syncthreads();
    }
    if (t == 0) bsum[blockIdx.x] = tmp[0];
}

__global__ void scan2_kernel(int* __restrict__ bsum, int nb) {
    __shared__ int tmp[1024];
    int t = threadIdx.x;
    int v = (t < nb) ? bsum[t] : 0;
    tmp[t] = v;
    for (int d = 1; d < 1024; d <<= 1) {
        __syncthreads();
        int u = (t >= d) ? tmp[t - d] : 0;
        __syncthreads();
        tmp[t] += u;
    }
    __syncthreads();
    if (t < nb) bsum[t] = tmp[t] - v;  // exclusive
}

__global__ void scan3_kernel(const int* __restrict__ cnt, const int* __restrict__ bsum,
                             int* __restrict__ off, int n2) {
    __shared__ int tmp[256];
    int t = threadIdx.x, i = blockIdx.x * 256 + t;
    int v = (i < n2) ? cnt[i] : 0;
    tmp[t] = v;
    for (int d = 1; d < 256; d <<= 1) {
        __syncthreads();
        int u = (t >= d) ? tmp[t - d] : 0;
        __syncthreads();
        tmp[t] += u;
    }
    __syncthreads();
    if (i < n2) off[i] = tmp[t] - v + bsum[blockIdx.x];
}

// Bucket-fill adjacency; store (neighbor, neighbor's dn) so gather has no
// dependent dn lookup. Row lists weight = dn_in[c]; col lists = dn_out[r].
__global__ void fill_kernel(const int* __restrict__ row, const int* __restrict__ col,
                            const float* __restrict__ dn,
                            int* __restrict__ off, int2* __restrict__ idx2, int N, int E) {
    int e = blockIdx.x * blockDim.x + threadIdx.x;
    if (e < E) {
        int r = row[e], c = col[e];
        int p = atomicAdd(&off[r], 1);
        idx2[p] = make_int2(c, __float_as_int(dn[N + c]));
        int q = atomicAdd(&off[N + c], 1);
        idx2[q] = make_int2(r, __float_as_int(dn[r]));
    }
}

// Pack x_real/x_imag (f32) -> Xp bf16 rows [xr pairs(64 words) | xi pairs(64 words)].
__global__ void pack_kernel(const float4* __restrict__ xr4, const float4* __restrict__ xi4,
                            uint2* __restrict__ Xp2, int N) {
    int t = blockIdx.x * blockDim.x + threadIdx.x;
    if (t >= N * 32) return;
    int n = t >> 5, q = t & 31;  // feats 4q..4q+3
    float4 r = xr4[(size_t)n * 32 + q];
    float4 m = xi4[(size_t)n * 32 + q];
    Xp2[(size_t)n * 64 + q] = make_uint2(pk(r.x, r.y), pk(r.z, r.w));
    Xp2[(size_t)n * 64 + 32 + q] = make_uint2(pk(m.x, m.y), pk(m.z, m.w));
}

// Combined per-path weights Wt[path][o][k] (bf16) and bias[path][o].
__global__ void weights_kernel(const float* __restrict__ Wr, const float* __restrict__ Wi,
                               const float* __restrict__ br, const float* __restrict__ bi,
                               unsigned short* __restrict__ Wt, float* __restrict__ bias) {
    int j = blockIdx.x * 256 + threadIdx.x;  // 0..65535
    int k = j & 255, o = (j >> 8) & 127, path = j >> 15;
    int i = k & 127;
    float wr = Wr[o * 128 + i] + 0.5f * Wr[16384 + o * 128 + i] + 0.25f * Wr[32768 + o * 128 + i];
    float wi = Wi[o * 128 + i] + 0.5f * Wi[16384 + o * 128 + i] + 0.25f * Wi[32768 + o * 128 + i];
    float v;
    if (path == 0) v = (k < 128) ? wr : -wi;
    else           v = (k < 128) ? wr : wi;
    Wt[j] = f2b(v);
    if (j < 256) {
        int oo = j & 127, p = j >> 7;
        float er = br[oo] + 0.5f * br[128 + oo] + 0.25f * br[256 + oo];
        float ei = bi[oo] + 0.5f * bi[128 + oo] + 0.25f * bi[256 + oo];
        bias[j] = p ? (er + ei) : (er - ei);
    }
}

// One 64-lane wave per node; lane holds features (2l, 2l+1). bf16 in, f32 acc.
__global__ __launch_bounds__(256) void gather_kernel(
        const int* __restrict__ off, const int* __restrict__ cnt,
        const int2* __restrict__ idx2, const float* __restrict__ dn,
        const unsigned* __restrict__ Xp,
        unsigned int* __restrict__ A, int N) {  // A rows: 192 uints
    int wave = (blockIdx.x * blockDim.x + threadIdx.x) >> 6;
    int lane = threadIdx.x & 63;
    if (wave >= N) return;
    int n = wave;

    float2 aR = {0.f, 0.f}, aI = {0.f, 0.f};
    {
        int end = off[n], start = end - cnt[n];
        for (int j = start; j < end; ++j) {
            int2 e = idx2[j];
            float w = __int_as_float(e.y);
            const unsigned* rp = Xp + (size_t)e.x * 128;
            float2 r = b2f2(rp[lane]);
            float2 m = b2f2(rp[64 + lane]);
            aR.x = fmaf(w, r.x, aR.x); aR.y = fmaf(w, r.y, aR.y);
            aI.x = fmaf(w, m.x, aI.x); aI.y = fmaf(w, m.y, aI.y);
        }
    }
    float2 bR = {0.f, 0.f}, bI = {0.f, 0.f};
    {
        int end = off[N + n], start = end - cnt[N + n];
        for (int j = start; j < end; ++j) {
            int2 e = idx2[j];
            float w = __int_as_float(e.y);
            const unsigned* rp = Xp + (size_t)e.x * 128;
            float2 r = b2f2(rp[lane]);
            float2 m = b2f2(rp[64 + lane]);
            bR.x = fmaf(w, r.x, bR.x); bR.y = fmaf(w, r.y, bR.y);
            bI.x = fmaf(w, m.x, bI.x); bI.y = fmaf(w, m.y, bI.y);
        }
    }
    float wo = dn[n], wi_ = dn[N + n];
    float yrx = wo * aR.x, yry = wo * aR.y;
    float ux = 0.5f * (yrx + wi_ * bR.x), uy = 0.5f * (yry + wi_ * bR.y);
    float vx = 0.5f * (wo * aI.x + wi_ * bI.x), vy = 0.5f * (wo * aI.y + wi_ * bI.y);
    unsigned int* rowp = A + (size_t)n * 192;
    rowp[lane]       = pk(ux, uy);
    rowp[64 + lane]  = pk(vx, vy);
    rowp[128 + lane] = pk(yrx, yry);
}

// BM=128, BN=128, K=256. 4 waves (2x2), 64x64 per wave. A via global_load_lds
// with source-side XOR swizzle; W fragments straight from global (L2-resident).
__global__ __launch_bounds__(256) void mfma_out_kernel(
        const unsigned short* __restrict__ A,   // [Npad][384]
        const unsigned short* __restrict__ Wt,  // [2][128][256]
        const float* __restrict__ bias,
        float* __restrict__ out, int N) {
    __shared__ unsigned short Alds[128 * 256];  // 64 KB
    int path = blockIdx.y;
    int mbase = blockIdx.x * 128;
    int tid = threadIdx.x;
    int lane = tid & 63, wid = tid >> 6;

    const unsigned short* Ag = A + (size_t)mbase * 384 + path * 128;
#pragma unroll
    for (int i = 0; i < 16; ++i) {
        int linear = i * 256 + tid;           // 16B-chunk index
        int row = linear >> 5, chunk = linear & 31;
        int gchunk = chunk ^ (row & 7);
        const unsigned short* gp = Ag + (size_t)row * 384 + gchunk * 8;
        char* lp = (char*)Alds + (size_t)(i * 256 + wid * 64) * 16;
        __builtin_amdgcn_global_load_lds(
            (const __attribute__((address_space(1))) void*)gp,
            (__attribute__((address_space(3))) void*)lp, 16, 0, 0);
    }
    __syncthreads();

    int wm = wid >> 1, wn = wid & 1;
    int r0 = wm * 64, c0 = wn * 64;
    f32x4 acc[4][4] = {};
    const unsigned short* Wp = Wt + ((size_t)path * 128 + c0 + (lane & 15)) * 256 + (lane >> 4) * 8;

    for (int kk = 0; kk < 8; ++kk) {
        bf16x8 b[4];
#pragma unroll
        for (int ni = 0; ni < 4; ++ni)
            b[ni] = *(const bf16x8*)(Wp + (size_t)ni * 16 * 256 + kk * 32);
        bf16x8 a[4];
#pragma unroll
        for (int mi = 0; mi < 4; ++mi) {
            int row = r0 + mi * 16 + (lane & 15);
            int chunk = (kk * 4 + (lane >> 4)) ^ (row & 7);
            a[mi] = *(const bf16x8*)(Alds + row * 256 + chunk * 8);
        }
#pragma unroll
        for (int mi = 0; mi < 4; ++mi)
#pragma unroll
            for (int ni = 0; ni < 4; ++ni)
                acc[mi][ni] = __builtin_amdgcn_mfma_f32_16x16x32_bf16(a[mi], b[ni], acc[mi][ni], 0, 0, 0);
    }

    size_t ND = (size_t)N * 128;
#pragma unroll
    for (int mi = 0; mi < 4; ++mi) {
#pragma unroll
        for (int ni = 0; ni < 4; ++ni) {
            int col = c0 + ni * 16 + (lane & 15);
            float bb = bias[path * 128 + col];
#pragma unroll
            for (int r = 0; r < 4; ++r) {
                int n = mbase + r0 + mi * 16 + (lane >> 4) * 4 + r;
                if (n < N) out[(size_t)path * ND + (size_t)n * 128 + col] = acc[mi][ni][r] + bb;
            }
        }
    }
}

extern "C" void kernel_launch(void* const* d_in, const int* in_sizes, int n_in,
                              void* d_out, int out_size, void* d_ws, size_t ws_size,
                              hipStream_t stream) {
    const float* x_real = (const float*)d_in[0];
    const float* x_imag = (const float*)d_in[1];
    const float* W_real = (const float*)d_in[2];
    const float* W_imag = (const float*)d_in[3];
    const float* b_real = (const float*)d_in[4];
    const float* b_imag = (const float*)d_in[5];
    const int* edge = (const int*)d_in[6];

    int N = in_sizes[0] / 128;
    int E = in_sizes[6] / 2;
    const int* row = edge;
    const int* col = edge + E;
    float* out = (float*)d_out;

    char* ws = (char*)d_ws;
    int n2 = 2 * N;
    int Npad = ((N + 127) / 128) * 128;
    int* cnt = (int*)ws;
    int* off = (int*)(ws + (size_t)n2 * 4);
    int* bsum = (int*)(ws + (size_t)2 * n2 * 4);
    float* dn = (float*)(ws + (size_t)2 * n2 * 4 + 4096);
    int2* idx2 = (int2*)(ws + (size_t)3 * n2 * 4 + 4096);
    unsigned* Xp = (unsigned*)((char*)idx2 + (size_t)2 * E * 8);
    unsigned short* Wt = (unsigned short*)((char*)Xp + (size_t)N * 128 * 4);
    float* bias = (float*)((char*)Wt + 2 * 128 * 256 * 2);
    unsigned short* A = (unsigned short*)((char*)bias + 256 * 4);

    int nb = (n2 + 255) / 256;  // <= 1024

    hipMemsetAsync(cnt, 0, (size_t)n2 * 4, stream);
    count_kernel<<<(E + 255) / 256, 256, 0, stream>>>(row, col, cnt, N, E);
    scan1_kernel<<<nb, 256, 0, stream>>>(cnt, bsum, dn, n2);
    scan2_kernel<<<1, 1024, 0, stream>>>(bsum, nb);
    scan3_kernel<<<nb, 256, 0, stream>>>(cnt, bsum, off, n2);
    fill_kernel<<<(E + 255) / 256, 256, 0, stream>>>(row, col, dn, off, idx2, N, E);
    pack_kernel<<<(N * 32 + 255) / 256, 256, 0, stream>>>((const float4*)x_real,
                                                          (const float4*)x_imag,
                                                          (uint2*)Xp, N);
    weights_kernel<<<256, 256, 0, stream>>>(W_real, W_imag, b_real, b_imag, Wt, bias);
    gather_kernel<<<(N * 64 + 255) / 256, 256, 0, stream>>>(off, cnt, idx2, dn,
                                                            Xp, (unsigned int*)A, N);
    dim3 gg(Npad / 128, 2);
    mfma_out_kernel<<<gg, 256, 0, stream>>>(A, Wt, bias, out, N);
}

// Round 5
// 433.888 us; speedup vs baseline: 11.2326x; 1.2425x over previous
//
#include <hip/hip_runtime.h>
#include <math.h>

// ComplexFaberConv — CSR gather over interleaved bf16 X -> bf16 A -> MFMA GEMM.
//
// Xp[n] = 64 x uint2 per row: lane l holds {xr[2l],xr[2l+1]} , {xi[2l],xi[2l+1]}
// A[n]  = [u(128) | v(128) | yr(128)] bf16, row stride 384.
//   u = 0.5*(y_r + y_rt), v = 0.5*(y_i + y_it), yr = y_r
// real = u@Wr_eff^T - v@Wi_eff^T + (br-bi)   (A k-slice [0:256))
// imag = v@Wr_eff^T + yr@Wi_eff^T + (br+bi)  (A k-slice [128:384))
//
// Workspace (N=100000, E=640000, Npad=100096):
//   cnt  int[2N], off int[2N], bsum int[1024], dn f32[2N]
//   rank int[2E]            (edge's rank within its bucket, from count)
//   idx2 int2[2E]           (neighbor, neighbor-dn bits)
//   Xp   uint2[N*64]        (51.2MB)
//   Wt   bf16[2][128][256], bias f32[2][128]
//   A    bf16[Npad][384]    (~76.9MB)
// Total ~146 MB.

typedef __bf16 bf16x8 __attribute__((ext_vector_type(8)));
typedef float f32x4 __attribute__((ext_vector_type(4)));

__device__ __forceinline__ unsigned short f2b(float f) {
    unsigned u = __float_as_uint(f);
    u += 0x7FFFu + ((u >> 16) & 1u);
    return (unsigned short)(u >> 16);
}
__device__ __forceinline__ unsigned pk(float lo, float hi) {
    return (unsigned)f2b(lo) | ((unsigned)f2b(hi) << 16);
}
__device__ __forceinline__ float2 b2f2(unsigned w) {
    return make_float2(__uint_as_float(w << 16), __uint_as_float(w & 0xFFFF0000u));
}

// Count degrees AND record each edge's rank within its bucket.
__global__ void count_kernel(const int* __restrict__ row, const int* __restrict__ col,
                             int* __restrict__ cnt, int* __restrict__ rank, int N, int E) {
    int e = blockIdx.x * blockDim.x + threadIdx.x;
    if (e < E) {
        rank[e] = atomicAdd(&cnt[row[e]], 1);
        rank[E + e] = atomicAdd(&cnt[N + col[e]], 1);
    }
}

// Per-256 block sums + dn = deg^-0.25.
__global__ void scan1_kernel(const int* __restrict__ cnt, int* __restrict__ bsum,
                             float* __restrict__ dn, int n2) {
    __shared__ int tmp[256];
    int t = threadIdx.x, i = blockIdx.x * 256 + t;
    int d = (i < n2) ? cnt[i] : 0;
    if (i < n2) dn[i] = (d > 0) ? rsqrtf(sqrtf((float)d)) : 0.0f;
    tmp[t] = d;
    __syncthreads();
    for (int s = 128; s > 0; s >>= 1) {
        if (t < s) tmp[t] += tmp[t + s];
        __syncthreads();
    }
    if (t == 0) bsum[blockIdx.x] = tmp[0];
}

__global__ void scan2_kernel(int* __restrict__ bsum, int nb) {
    __shared__ int tmp[1024];
    int t = threadIdx.x;
    int v = (t < nb) ? bsum[t] : 0;
    tmp[t] = v;
    for (int d = 1; d < 1024; d <<= 1) {
        __syncthreads();
        int u = (t >= d) ? tmp[t - d] : 0;
        __syncthreads();
        tmp[t] += u;
    }
    __syncthreads();
    if (t < nb) bsum[t] = tmp[t] - v;  // exclusive
}

__global__ void scan3_kernel(const int* __restrict__ cnt, const int* __restrict__ bsum,
                             int* __restrict__ off, int n2) {
    __shared__ int tmp[256];
    int t = threadIdx.x, i = blockIdx.x * 256 + t;
    int v = (i < n2) ? cnt[i] : 0;
    tmp[t] = v;
    for (int d = 1; d < 256; d <<= 1) {
        __syncthreads();
        int u = (t >= d) ? tmp[t - d] : 0;
        __syncthreads();
        tmp[t] += u;
    }
    __syncthreads();
    if (i < n2) off[i] = tmp[t] - v + bsum[blockIdx.x];
}

// Atomic-free bucket fill using precomputed ranks. off stays pristine (exclusive).
__global__ void fill_kernel(const int* __restrict__ row, const int* __restrict__ col,
                            const float* __restrict__ dn, const int* __restrict__ off,
                            const int* __restrict__ rank, int2* __restrict__ idx2,
                            int N, int E) {
    int e = blockIdx.x * blockDim.x + threadIdx.x;
    if (e < E) {
        int r = row[e], c = col[e];
        idx2[off[r] + rank[e]] = make_int2(c, __float_as_int(dn[N + c]));
        idx2[off[N + c] + rank[E + e]] = make_int2(r, __float_as_int(dn[r]));
    }
}

// Pack x_real/x_imag (f32) -> interleaved bf16 rows: lane l gets {xr pair, xi pair}.
__global__ void pack_kernel(const float4* __restrict__ xr4, const float4* __restrict__ xi4,
                            uint4* __restrict__ Xp4, int N) {
    int t = blockIdx.x * blockDim.x + threadIdx.x;
    if (t >= N * 32) return;
    int n = t >> 5, q = t & 31;  // feats 4q..4q+3 -> lanes 2q, 2q+1
    float4 r = xr4[(size_t)n * 32 + q];
    float4 m = xi4[(size_t)n * 32 + q];
    Xp4[(size_t)n * 32 + q] = make_uint4(pk(r.x, r.y), pk(m.x, m.y),
                                         pk(r.z, r.w), pk(m.z, m.w));
}

// Combined per-path weights Wt[path][o][k] (bf16) and bias[path][o].
__global__ void weights_kernel(const float* __restrict__ Wr, const float* __restrict__ Wi,
                               const float* __restrict__ br, const float* __restrict__ bi,
                               unsigned short* __restrict__ Wt, float* __restrict__ bias) {
    int j = blockIdx.x * 256 + threadIdx.x;  // 0..65535
    int k = j & 255, o = (j >> 8) & 127, path = j >> 15;
    int i = k & 127;
    float wr = Wr[o * 128 + i] + 0.5f * Wr[16384 + o * 128 + i] + 0.25f * Wr[32768 + o * 128 + i];
    float wi = Wi[o * 128 + i] + 0.5f * Wi[16384 + o * 128 + i] + 0.25f * Wi[32768 + o * 128 + i];
    float v;
    if (path == 0) v = (k < 128) ? wr : -wi;
    else           v = (k < 128) ? wr : wi;
    Wt[j] = f2b(v);
    if (j < 256) {
        int oo = j & 127, p = j >> 7;
        float er = br[oo] + 0.5f * br[128 + oo] + 0.25f * br[256 + oo];
        float ei = bi[oo] + 0.5f * bi[128 + oo] + 0.25f * bi[256 + oo];
        bias[j] = p ? (er + ei) : (er - ei);
    }
}

// One 64-lane wave per node. Merged dual-direction loop, unroll x2 each ->
// up to 4 independent 512B row streams in flight per wave.
__global__ __launch_bounds__(256) void gather_kernel(
        const int* __restrict__ off, const int* __restrict__ cnt,
        const int2* __restrict__ idx2, const float* __restrict__ dn,
        const uint2* __restrict__ Xp,
        unsigned int* __restrict__ A, int N) {  // A rows: 192 uints
    int wave = (blockIdx.x * blockDim.x + threadIdx.x) >> 6;
    int lane = threadIdx.x & 63;
    if (wave >= N) return;
    int n = wave;

    float aRx = 0.f, aRy = 0.f, aIx = 0.f, aIy = 0.f;
    float bRx = 0.f, bRy = 0.f, bIx = 0.f, bIy = 0.f;
    int s1 = off[n], c1 = cnt[n];
    int s2 = off[N + n], c2 = cnt[N + n];
    int k1 = 0, k2 = 0;
    int L1 = c1 & ~1, L2 = c2 & ~1;

    while (k1 < L1 && k2 < L2) {
        int2 ea = idx2[s1 + k1], eb = idx2[s1 + k1 + 1];
        int2 ec = idx2[s2 + k2], ed = idx2[s2 + k2 + 1];
        uint2 da = Xp[(size_t)ea.x * 64 + lane];
        uint2 db = Xp[(size_t)eb.x * 64 + lane];
        uint2 dc = Xp[(size_t)ec.x * 64 + lane];
        uint2 dd = Xp[(size_t)ed.x * 64 + lane];
        float wa = __int_as_float(ea.y), wb = __int_as_float(eb.y);
        float wc = __int_as_float(ec.y), wd = __int_as_float(ed.y);
        float2 t;
        t = b2f2(da.x); aRx = fmaf(wa, t.x, aRx); aRy = fmaf(wa, t.y, aRy);
        t = b2f2(da.y); aIx = fmaf(wa, t.x, aIx); aIy = fmaf(wa, t.y, aIy);
        t = b2f2(db.x); aRx = fmaf(wb, t.x, aRx); aRy = fmaf(wb, t.y, aRy);
        t = b2f2(db.y); aIx = fmaf(wb, t.x, aIx); aIy = fmaf(wb, t.y, aIy);
        t = b2f2(dc.x); bRx = fmaf(wc, t.x, bRx); bRy = fmaf(wc, t.y, bRy);
        t = b2f2(dc.y); bIx = fmaf(wc, t.x, bIx); bIy = fmaf(wc, t.y, bIy);
        t = b2f2(dd.x); bRx = fmaf(wd, t.x, bRx); bRy = fmaf(wd, t.y, bRy);
        t = b2f2(dd.y); bIx = fmaf(wd, t.x, bIx); bIy = fmaf(wd, t.y, bIy);
        k1 += 2; k2 += 2;
    }
    while (k1 < L1) {
        int2 ea = idx2[s1 + k1], eb = idx2[s1 + k1 + 1];
        uint2 da = Xp[(size_t)ea.x * 64 + lane];
        uint2 db = Xp[(size_t)eb.x * 64 + lane];
        float wa = __int_as_float(ea.y), wb = __int_as_float(eb.y);
        float2 t;
        t = b2f2(da.x); aRx = fmaf(wa, t.x, aRx); aRy = fmaf(wa, t.y, aRy);
        t = b2f2(da.y); aIx = fmaf(wa, t.x, aIx); aIy = fmaf(wa, t.y, aIy);
        t = b2f2(db.x); aRx = fmaf(wb, t.x, aRx); aRy = fmaf(wb, t.y, aRy);
        t = b2f2(db.y); aIx = fmaf(wb, t.x, aIx); aIy = fmaf(wb, t.y, aIy);
        k1 += 2;
    }
    while (k2 < L2) {
        int2 ec = idx2[s2 + k2], ed = idx2[s2 + k2 + 1];
        uint2 dc = Xp[(size_t)ec.x * 64 + lane];
        uint2 dd = Xp[(size_t)ed.x * 64 + lane];
        float wc = __int_as_float(ec.y), wd = __int_as_float(ed.y);
        float2 t;
        t = b2f2(dc.x); bRx = fmaf(wc, t.x, bRx); bRy = fmaf(wc, t.y, bRy);
        t = b2f2(dc.y); bIx = fmaf(wc, t.x, bIx); bIy = fmaf(wc, t.y, bIy);
        t = b2f2(dd.x); bRx = fmaf(wd, t.x, bRx); bRy = fmaf(wd, t.y, bRy);
        t = b2f2(dd.y); bIx = fmaf(wd, t.x, bIx); bIy = fmaf(wd, t.y, bIy);
        k2 += 2;
    }
    if (k1 < c1) {
        int2 ea = idx2[s1 + k1];
        uint2 da = Xp[(size_t)ea.x * 64 + lane];
        float wa = __int_as_float(ea.y);
        float2 t;
        t = b2f2(da.x); aRx = fmaf(wa, t.x, aRx); aRy = fmaf(wa, t.y, aRy);
        t = b2f2(da.y); aIx = fmaf(wa, t.x, aIx); aIy = fmaf(wa, t.y, aIy);
    }
    if (k2 < c2) {
        int2 ec = idx2[s2 + k2];
        uint2 dc = Xp[(size_t)ec.x * 64 + lane];
        float wc = __int_as_float(ec.y);
        float2 t;
        t = b2f2(dc.x); bRx = fmaf(wc, t.x, bRx); bRy = fmaf(wc, t.y, bRy);
        t = b2f2(dc.y); bIx = fmaf(wc, t.x, bIx); bIy = fmaf(wc, t.y, bIy);
    }

    float wo = dn[n], wi_ = dn[N + n];
    float yrx = wo * aRx, yry = wo * aRy;
    float ux = 0.5f * (yrx + wi_ * bRx), uy = 0.5f * (yry + wi_ * bRy);
    float vx = 0.5f * (wo * aIx + wi_ * bIx), vy = 0.5f * (wo * aIy + wi_ * bIy);
    unsigned int* rowp = A + (size_t)n * 192;
    rowp[lane]       = pk(ux, uy);
    rowp[64 + lane]  = pk(vx, vy);
    rowp[128 + lane] = pk(yrx, yry);
}

// BM=128, BN=128, K=256. 4 waves (2x2), 64x64 per wave. A via global_load_lds
// with source-side XOR swizzle; W fragments straight from global (L2-resident).
__global__ __launch_bounds__(256) void mfma_out_kernel(
        const unsigned short* __restrict__ A,   // [Npad][384]
        const unsigned short* __restrict__ Wt,  // [2][128][256]
        const float* __restrict__ bias,
        float* __restrict__ out, int N) {
    __shared__ unsigned short Alds[128 * 256];  // 64 KB
    int path = blockIdx.y;
    int mbase = blockIdx.x * 128;
    int tid = threadIdx.x;
    int lane = tid & 63, wid = tid >> 6;

    const unsigned short* Ag = A + (size_t)mbase * 384 + path * 128;
#pragma unroll
    for (int i = 0; i < 16; ++i) {
        int linear = i * 256 + tid;           // 16B-chunk index
        int row = linear >> 5, chunk = linear & 31;
        int gchunk = chunk ^ (row & 7);
        const unsigned short* gp = Ag + (size_t)row * 384 + gchunk * 8;
        char* lp = (char*)Alds + (size_t)(i * 256 + wid * 64) * 16;
        __builtin_amdgcn_global_load_lds(
            (const __attribute__((address_space(1))) void*)gp,
            (__attribute__((address_space(3))) void*)lp, 16, 0, 0);
    }
    __syncthreads();

    int wm = wid >> 1, wn = wid & 1;
    int r0 = wm * 64, c0 = wn * 64;
    f32x4 acc[4][4] = {};
    const unsigned short* Wp = Wt + ((size_t)path * 128 + c0 + (lane & 15)) * 256 + (lane >> 4) * 8;

    for (int kk = 0; kk < 8; ++kk) {
        bf16x8 b[4];
#pragma unroll
        for (int ni = 0; ni < 4; ++ni)
            b[ni] = *(const bf16x8*)(Wp + (size_t)ni * 16 * 256 + kk * 32);
        bf16x8 a[4];
#pragma unroll
        for (int mi = 0; mi < 4; ++mi) {
            int row = r0 + mi * 16 + (lane & 15);
            int chunk = (kk * 4 + (lane >> 4)) ^ (row & 7);
            a[mi] = *(const bf16x8*)(Alds + row * 256 + chunk * 8);
        }
#pragma unroll
        for (int mi = 0; mi < 4; ++mi)
#pragma unroll
            for (int ni = 0; ni < 4; ++ni)
                acc[mi][ni] = __builtin_amdgcn_mfma_f32_16x16x32_bf16(a[mi], b[ni], acc[mi][ni], 0, 0, 0);
    }

    size_t ND = (size_t)N * 128;
#pragma unroll
    for (int mi = 0; mi < 4; ++mi) {
#pragma unroll
        for (int ni = 0; ni < 4; ++ni) {
            int col = c0 + ni * 16 + (lane & 15);
            float bb = bias[path * 128 + col];
#pragma unroll
            for (int r = 0; r < 4; ++r) {
                int n = mbase + r0 + mi * 16 + (lane >> 4) * 4 + r;
                if (n < N) out[(size_t)path * ND + (size_t)n * 128 + col] = acc[mi][ni][r] + bb;
            }
        }
    }
}

extern "C" void kernel_launch(void* const* d_in, const int* in_sizes, int n_in,
                              void* d_out, int out_size, void* d_ws, size_t ws_size,
                              hipStream_t stream) {
    const float* x_real = (const float*)d_in[0];
    const float* x_imag = (const float*)d_in[1];
    const float* W_real = (const float*)d_in[2];
    const float* W_imag = (const float*)d_in[3];
    const float* b_real = (const float*)d_in[4];
    const float* b_imag = (const float*)d_in[5];
    const int* edge = (const int*)d_in[6];

    int N = in_sizes[0] / 128;
    int E = in_sizes[6] / 2;
    const int* row = edge;
    const int* col = edge + E;
    float* out = (float*)d_out;

    char* ws = (char*)d_ws;
    int n2 = 2 * N;
    int Npad = ((N + 127) / 128) * 128;
    int* cnt = (int*)ws;
    int* off = (int*)(ws + (size_t)n2 * 4);
    int* bsum = (int*)(ws + (size_t)2 * n2 * 4);
    float* dn = (float*)(ws + (size_t)2 * n2 * 4 + 4096);
    int* rankp = (int*)(ws + (size_t)3 * n2 * 4 + 4096);
    int2* idx2 = (int2*)((char*)rankp + (size_t)2 * E * 4);
    uint2* Xp = (uint2*)((char*)idx2 + (size_t)2 * E * 8);
    unsigned short* Wt = (unsigned short*)((char*)Xp + (size_t)N * 512);
    float* bias = (float*)((char*)Wt + 2 * 128 * 256 * 2);
    unsigned short* A = (unsigned short*)((char*)bias + 256 * 4);

    int nb = (n2 + 255) / 256;  // <= 1024

    hipMemsetAsync(cnt, 0, (size_t)n2 * 4, stream);
    count_kernel<<<(E + 255) / 256, 256, 0, stream>>>(row, col, cnt, rankp, N, E);
    scan1_kernel<<<nb, 256, 0, stream>>>(cnt, bsum, dn, n2);
    scan2_kernel<<<1, 1024, 0, stream>>>(bsum, nb);
    scan3_kernel<<<nb, 256, 0, stream>>>(cnt, bsum, off, n2);
    fill_kernel<<<(E + 255) / 256, 256, 0, stream>>>(row, col, dn, off, rankp, idx2, N, E);
    pack_kernel<<<(N * 32 + 255) / 256, 256, 0, stream>>>((const float4*)x_real,
                                                          (const float4*)x_imag,
                                                          (uint4*)Xp, N);
    weights_kernel<<<256, 256, 0, stream>>>(W_real, W_imag, b_real, b_imag, Wt, bias);
    gather_kernel<<<(N * 64 + 255) / 256, 256, 0, stream>>>(off, cnt, idx2, dn,
                                                            Xp, (unsigned int*)A, N);
    dim3 gg(Npad / 128, 2);
    mfma_out_kernel<<<gg, 256, 0, stream>>>(A, Wt, bias, out, N);
}